// Round 3
// baseline (1592.873 us; speedup 1.0000x reference)
//
#include <hip/hip_runtime.h>
#include <math.h>

#define NB 256
#define NT 1024
#define ND 32
#define NH 64
#define NL 32
#define DT0 0.4f
#define XB 36   // LDS row stride for staged x: [ys(32), ts(1), pad(3)] -> 144B, 16B-aligned

__device__ __forceinline__ float dot4(float4 a, float4 b) {
    return a.x * b.x + a.y * b.y + a.z * b.z + a.w * b.w;
}
__device__ __forceinline__ float fsigm(float x) {
    return __fdividef(1.0f, 1.0f + __expf(-x));
}
__device__ __forceinline__ float ftanh(float x) {
    float cx = fminf(fmaxf(x, -15.0f), 15.0f);
    float e2 = __expf(2.0f * cx);
    return __fdividef(e2 - 1.0f, e2 + 1.0f);
}
__device__ __forceinline__ float fsoftplus(float x) {
    return fmaxf(x, 0.0f) + __logf(1.0f + __expf(-fabsf(x)));
}

// load wi row (33 floats, 4B-aligned): [0]=ts weight, [1..32]=y weights
#define LDROW(A, g) do { \
    A##0 = make_float4((g)[1],(g)[2],(g)[3],(g)[4]); \
    A##1 = make_float4((g)[5],(g)[6],(g)[7],(g)[8]); \
    A##2 = make_float4((g)[9],(g)[10],(g)[11],(g)[12]); \
    A##3 = make_float4((g)[13],(g)[14],(g)[15],(g)[16]); \
    A##4 = make_float4((g)[17],(g)[18],(g)[19],(g)[20]); \
    A##5 = make_float4((g)[21],(g)[22],(g)[23],(g)[24]); \
    A##6 = make_float4((g)[25],(g)[26],(g)[27],(g)[28]); \
    A##7 = make_float4((g)[29],(g)[30],(g)[31],(g)[32]); \
} while (0)

extern "C" __global__ void __launch_bounds__(256, 1)
latentode_fused(const float* __restrict__ ts,      // (B,T)
                const float* __restrict__ ys,      // (B,T,D)
                const float* __restrict__ eps,     // (B,L)
                const float* __restrict__ scale_p, // ()
                const float* __restrict__ fw0, const float* __restrict__ fb0,
                const float* __restrict__ fw1, const float* __restrict__ fb1,
                const float* __restrict__ fw2, const float* __restrict__ fb2,
                const float* __restrict__ gwi, const float* __restrict__ gwh,
                const float* __restrict__ gb,  const float* __restrict__ gbn,
                const float* __restrict__ hlw, const float* __restrict__ hlb,
                const float* __restrict__ lw0, const float* __restrict__ lb0,
                const float* __restrict__ lw1, const float* __restrict__ lb1,
                const float* __restrict__ lw2, const float* __restrict__ lb2,
                const float* __restrict__ hdw, const float* __restrict__ hdb,
                float* __restrict__ out)
{
    const int b   = blockIdx.x;
    const int tid = threadIdx.x;
    const int w   = tid >> 6;
    const int ln  = tid & 63;

    // ---- LDS: 154 KB total (1 block/CU; gfx950 allows up to 160 KB static) ----
    __shared__ __align__(16) float xb[NT * XB];        // 147456 B staged input
    __shared__ __align__(16) float hbw[192];           // per-wave h copies (waves 0-2)
    __shared__ __align__(16) float hacc4[2][64][4];    // dbuf {hr,hz,hn,-}
    __shared__ __align__(16) float igb[2][64][4];      // dbuf {xr,xz,xn,-} (bias folded)
    __shared__ __align__(16) float ybw[192];           // per-wave y copies (waves 0-2)
    __shared__ __align__(16) float a0b[64];
    __shared__ __align__(16) float a1b[64];
    __shared__ __align__(16) float tmpb[64];
    __shared__ __align__(16) float latb[32];
    __shared__ float redr[32];

    // ================= stage ALL of ts/ys for this batch into LDS ==============
    for (int i = tid; i < NT * 8; i += 256) {
        const int row = i >> 3, q = i & 7;
        const float4 v = *(const float4*)(ys + (size_t)(b * NT + row) * ND + q * 4);
        *(float4*)&xb[row * XB + q * 4] = v;
    }
    for (int i = tid; i < NT; i += 256) xb[i * XB + 32] = ts[b * NT + i];
    if (tid < 192) hbw[tid] = 0.0f;

    // ================= GRU weights (named regs) ================================
    // waves 0-2: wh row tid (gate-group w, unit ln)
    float4 W0,W1,W2,W3,W4,W5,W6,W7,W8,W9,W10,W11,W12,W13,W14,W15;
    {
        const int r = (tid < 192) ? tid : 0;
        const float4* wp = (const float4*)(gwh + r * 64);
        W0=wp[0];  W1=wp[1];  W2=wp[2];  W3=wp[3];
        W4=wp[4];  W5=wp[5];  W6=wp[6];  W7=wp[7];
        W8=wp[8];  W9=wp[9];  W10=wp[10];W11=wp[11];
        W12=wp[12];W13=wp[13];W14=wp[14];W15=wp[15];
    }
    // wave 3: wi rows ln, 64+ln, 128+ln
    float4 P0,P1,P2,P3,P4,P5,P6,P7;
    float4 Q0,Q1,Q2,Q3,Q4,Q5,Q6,Q7;
    float4 R0,R1,R2,R3,R4,R5,R6,R7;
    float Pt=0.f, Qt=0.f, Rt=0.f, gbr=0.f, gbz=0.f, gbnb=0.f;
    if (w == 3) {
        const float* gr = gwi + ln * 33;
        const float* gz = gwi + (64 + ln) * 33;
        const float* gn = gwi + (128 + ln) * 33;
        Pt = gr[0]; Qt = gz[0]; Rt = gn[0];
        LDROW(P, gr); LDROW(Q, gz); LDROW(R, gn);
        gbr = gb[ln]; gbz = gb[64 + ln]; gbnb = gb[128 + ln];
    }
    const float bnv = (w < 3) ? gbn[ln] : 0.0f;

    __syncthreads();   // staging visible; also drains the weight loads

    // wave3: ig for s=0 (visible to B(0) via the A(0) barrier)
    if (w == 3) {
        const float* xrow = &xb[0];
        const float4* xv = (const float4*)xrow;
        const float4 x0=xv[0],x1=xv[1],x2=xv[2],x3=xv[3],x4=xv[4],x5=xv[5],x6=xv[6],x7=xv[7];
        const float tsv = xrow[32];
        float xr = gbr + Pt*tsv + dot4(P0,x0)+dot4(P1,x1)+dot4(P2,x2)+dot4(P3,x3)
                 + dot4(P4,x4)+dot4(P5,x5)+dot4(P6,x6)+dot4(P7,x7);
        float xz = gbz + Qt*tsv + dot4(Q0,x0)+dot4(Q1,x1)+dot4(Q2,x2)+dot4(Q3,x3)
                 + dot4(Q4,x4)+dot4(Q5,x5)+dot4(Q6,x6)+dot4(Q7,x7);
        float xn = gbnb + Rt*tsv + dot4(R0,x0)+dot4(R1,x1)+dot4(R2,x2)+dot4(R3,x3)
                 + dot4(R4,x4)+dot4(R5,x5)+dot4(R6,x6)+dot4(R7,x7);
        *(float4*)igb[0][ln] = make_float4(xr, xz, xn, 0.0f);
    }

    // ================= GRU scan: ONE barrier per step ==========================
    float hreg = 0.0f;
    for (int s = 0; s < NT; ++s) {
        const int pp = s & 1;
        float xr = 0.f, xz = 0.f, xn = 0.f;
        if (w < 3) {
            // h-dot from OWN h copy (written by this wave last step: lgkm-ordered)
            const float4* hv = (const float4*)&hbw[w * 64];
            const float4 h0=hv[0],h1=hv[1],h2=hv[2],h3=hv[3],h4=hv[4],h5=hv[5],h6=hv[6],h7=hv[7];
            const float4 h8=hv[8],h9=hv[9],h10=hv[10],h11=hv[11],h12=hv[12],h13=hv[13],h14=hv[14],h15=hv[15];
            float a0 = dot4(W0,h0) + dot4(W4,h4) + dot4(W8,h8)  + dot4(W12,h12);
            float a1 = dot4(W1,h1) + dot4(W5,h5) + dot4(W9,h9)  + dot4(W13,h13);
            float a2 = dot4(W2,h2) + dot4(W6,h6) + dot4(W10,h10)+ dot4(W14,h14);
            float a3 = dot4(W3,h3) + dot4(W7,h7) + dot4(W11,h11)+ dot4(W15,h15);
            hacc4[pp][ln][w] = (a0 + a1) + (a2 + a3);
        } else {
            // x-projection for step s+1 (row NT at s=NT-1 reads in-bounds garbage; unused)
            const float* xrow = &xb[(s + 1) * XB];
            const float4* xv = (const float4*)xrow;
            const float4 x0=xv[0],x1=xv[1],x2=xv[2],x3=xv[3],x4=xv[4],x5=xv[5],x6=xv[6],x7=xv[7];
            const float tsv = xrow[32];
            float pA = gbr + Pt*tsv + dot4(P0,x0) + dot4(P2,x2) + dot4(P4,x4) + dot4(P6,x6);
            float pB = dot4(P1,x1) + dot4(P3,x3) + dot4(P5,x5) + dot4(P7,x7);
            xr = pA + pB;
            float qA = gbz + Qt*tsv + dot4(Q0,x0) + dot4(Q2,x2) + dot4(Q4,x4) + dot4(Q6,x6);
            float qB = dot4(Q1,x1) + dot4(Q3,x3) + dot4(Q5,x5) + dot4(Q7,x7);
            xz = qA + qB;
            float rA = gbnb + Rt*tsv + dot4(R0,x0) + dot4(R2,x2) + dot4(R4,x4) + dot4(R6,x6);
            float rB = dot4(R1,x1) + dot4(R3,x3) + dot4(R5,x5) + dot4(R7,x7);
            xn = rA + rB;
        }
        __syncthreads();
        if (w < 3) {
            // redundant gate update: h is lane-local, each wave keeps its own copy
            const float4 ha = *(const float4*)hacc4[pp][ln];
            const float4 ia = *(const float4*)igb[pp][ln];
            const float rg = fsigm(ia.x + ha.x);
            const float zg = fsigm(ia.y + ha.y);
            const float ng = ftanh(ia.z + rg * (ha.z + bnv));
            hreg = ng + zg * (hreg - ng);
            hbw[w * 64 + ln] = hreg;
        } else {
            *(float4*)igb[pp ^ 1][ln] = make_float4(xr, xz, xn, 0.0f);
        }
    }
    __syncthreads();   // final h in hbw[0..63]

    // ================= context -> latent -> y0 =================================
    if (tid < 64) {
        const float4* wp = (const float4*)(hlw + tid * 64);
        const float4* hv = (const float4*)&hbw[0];
        float a0 = hlb[tid], a1 = 0.0f;
#pragma unroll
        for (int q = 0; q < 16; q += 2) { a0 += dot4(wp[q], hv[q]); a1 += dot4(wp[q+1], hv[q+1]); }
        tmpb[tid] = a0 + a1;
    }
    __syncthreads();
    float klpart = 0.0f;
    if (tid < 32) {
        const float mean   = tmpb[tid];
        const float logstd = tmpb[32 + tid];
        const float stdv   = __expf(logstd);
        latb[tid] = mean + eps[b * NL + tid] * stdv;
        klpart = 0.5f * (mean * mean + stdv * stdv - 2.0f * logstd - 1.0f);
    }
    __syncthreads();
    if (tid < 64) {
        const float4* wp = (const float4*)(lw0 + tid * 32);
        const float4* lv = (const float4*)latb;
        float a0 = lb0[tid], a1 = 0.0f;
#pragma unroll
        for (int q = 0; q < 8; q += 2) { a0 += dot4(wp[q], lv[q]); a1 += dot4(wp[q+1], lv[q+1]); }
        a0b[tid] = fmaxf(a0 + a1, 0.0f);
    }
    __syncthreads();
    if (tid < 64) {
        const float4* wp = (const float4*)(lw1 + tid * 64);
        const float4* av = (const float4*)a0b;
        float a0 = lb1[tid], a1 = 0.0f;
#pragma unroll
        for (int q = 0; q < 16; q += 2) { a0 += dot4(wp[q], av[q]); a1 += dot4(wp[q+1], av[q+1]); }
        a1b[tid] = fmaxf(a0 + a1, 0.0f);
    }
    __syncthreads();
    if (tid < 64) {
        const float4* wp = (const float4*)(lw2 + tid * 64);
        const float4* tv = (const float4*)a1b;
        float a0 = lb2[tid], a1 = 0.0f;
#pragma unroll
        for (int q = 0; q < 16; q += 2) { a0 += dot4(wp[q], tv[q]); a1 += dot4(wp[q+1], tv[q+1]); }
        tmpb[tid] = a0 + a1;   // y0
    }
    __syncthreads();

    // ================= Euler weights (named regs) ==============================
    // P1: wave0 -> fw0 rows 0-31, wave1 -> fw0 rows 32-63, wave2 -> hdw (2-way k-split)
    const int kh = ln >> 5, rr = ln & 31;
    float4 F0,F1,F2,F3,F4,F5,F6,F7;
    float fbias = 0.0f, hdbias = 0.0f;
    int prow = rr;
    if (w == 0 || w == 1) {
        prow = (w << 5) + rr;
        const float4* fp = (const float4*)(fw0 + prow * 64 + kh * 32);
        F0=fp[0];F1=fp[1];F2=fp[2];F3=fp[3];F4=fp[4];F5=fp[5];F6=fp[6];F7=fp[7];
        fbias = fb0[prow];
    } else if (w == 2) {
        const float4* fp = (const float4*)(hdw + rr * 64 + kh * 32);
        F0=fp[0];F1=fp[1];F2=fp[2];F3=fp[3];F4=fp[4];F5=fp[5];F6=fp[6];F7=fp[7];
        hdbias = hdb[rr];
    }
    // P2: all threads, 4-way k-split over fw1
    const int er = tid >> 2, ep = tid & 3;
    const float4* p1w = (const float4*)(fw1 + er * 64 + ep * 16);
    const float4 E10=p1w[0],E11=p1w[1],E12=p1w[2],E13=p1w[3];
    const float eb1 = fb1[er];
    // P3: waves 0-2, full fw2 row ln (redundant per wave)
    float4 G0,G1,G2,G3,G4,G5,G6,G7,G8,G9,G10,G11,G12,G13,G14,G15;
    float eb2 = 0.0f;
    if (w < 3) {
        const float4* gp = (const float4*)(fw2 + ln * 64);
        G0=gp[0];  G1=gp[1];  G2=gp[2];  G3=gp[3];
        G4=gp[4];  G5=gp[5];  G6=gp[6];  G7=gp[7];
        G8=gp[8];  G9=gp[9];  G10=gp[10];G11=gp[11];
        G12=gp[12];G13=gp[13];G14=gp[14];G15=gp[15];
        eb2 = fb2[ln];
    }
    const float dts = DT0 * scale_p[0];
    float yl = tmpb[ln];               // y0 (barrier above orders this)
    if (w < 3) ybw[w * 64 + ln] = yl;  // own copy; consumed same-wave
    float rec = 0.0f;

    // ================= Euler scan: TWO barriers per step =======================
    for (int s = 0; s < NT; ++s) {
        // ---- P1: layer0 (waves 0,1) | hd-proj + recon (wave 2) ----
        if (w <= 1) {
            const float4* yv = (const float4*)&ybw[w * 64];
            float a = dot4(F0,yv[kh*8+0]) + dot4(F2,yv[kh*8+2]) + dot4(F4,yv[kh*8+4]) + dot4(F6,yv[kh*8+6]);
            float c = dot4(F1,yv[kh*8+1]) + dot4(F3,yv[kh*8+3]) + dot4(F5,yv[kh*8+5]) + dot4(F7,yv[kh*8+7]);
            a += c;
            a += __shfl_xor(a, 32);
            if (kh == 0) a0b[prow] = fsoftplus(a + fbias);
        } else if (w == 2) {
            const float4* yv = (const float4*)&ybw[128];
            float a = dot4(F0,yv[kh*8+0]) + dot4(F2,yv[kh*8+2]) + dot4(F4,yv[kh*8+4]) + dot4(F6,yv[kh*8+6]);
            float c = dot4(F1,yv[kh*8+1]) + dot4(F3,yv[kh*8+3]) + dot4(F5,yv[kh*8+5]) + dot4(F7,yv[kh*8+7]);
            a += c;
            a += __shfl_xor(a, 32);
            if (kh == 0 && s > 0) {
                const float yd = xb[(s - 1) * XB + rr];
                const float d = yd - (a + hdbias);
                rec += d * d;
            }
        }
        __syncthreads();
        // ---- P2: layer1 (all 256 threads) ----
        {
            const float4* av = (const float4*)a0b;
            float a = dot4(E10, av[ep*4+0]) + dot4(E11, av[ep*4+1])
                    + dot4(E12, av[ep*4+2]) + dot4(E13, av[ep*4+3]);
            a += __shfl_xor(a, 1);
            a += __shfl_xor(a, 2);
            if (ep == 0) a1b[er] = fsoftplus(a + eb1);
        }
        __syncthreads();
        // ---- P3: layer2 + y update, redundant per wave (no barrier to next P1) ----
        if (w < 3) {
            const float4* av = (const float4*)a1b;
            float t0 = dot4(G0,av[0]) + dot4(G4,av[4]) + dot4(G8,av[8])  + dot4(G12,av[12]);
            float t1 = dot4(G1,av[1]) + dot4(G5,av[5]) + dot4(G9,av[9])  + dot4(G13,av[13]);
            float t2 = dot4(G2,av[2]) + dot4(G6,av[6]) + dot4(G10,av[10])+ dot4(G14,av[14]);
            float t3 = dot4(G3,av[3]) + dot4(G7,av[7]) + dot4(G11,av[11])+ dot4(G15,av[15]);
            yl += dts * ftanh((t0 + t1) + (t2 + t3) + eb2);
            ybw[w * 64 + ln] = yl;
        }
    }

    // ---- epilogue: pred for y_T vs ys[T-1] (wave 2, own y copy) ----
    if (w == 2) {
        const float4* yv = (const float4*)&ybw[128];
        float a = dot4(F0,yv[kh*8+0]) + dot4(F2,yv[kh*8+2]) + dot4(F4,yv[kh*8+4]) + dot4(F6,yv[kh*8+6]);
        float c = dot4(F1,yv[kh*8+1]) + dot4(F3,yv[kh*8+3]) + dot4(F5,yv[kh*8+5]) + dot4(F7,yv[kh*8+7]);
        a += c;
        a += __shfl_xor(a, 32);
        if (kh == 0) {
            const float yd = xb[(NT - 1) * XB + rr];
            const float d = yd - (a + hdbias);
            rec += d * d;
            redr[rr] = rec;
        }
    }
    // KL reduce (lanes 0-31 of wave 0 hold klpart)
    float klv = klpart;
    klv += __shfl_xor(klv, 1);
    klv += __shfl_xor(klv, 2);
    klv += __shfl_xor(klv, 4);
    klv += __shfl_xor(klv, 8);
    klv += __shfl_xor(klv, 16);
    __syncthreads();
    if (tid == 0) {
        float rs = 0.0f;
#pragma unroll
        for (int k2 = 0; k2 < 32; ++k2) rs += redr[k2];
        out[b] = 0.5f * rs + klv;
    }
}

extern "C" void kernel_launch(void* const* d_in, const int* in_sizes, int n_in,
                              void* d_out, int out_size, void* d_ws, size_t ws_size,
                              hipStream_t stream) {
    (void)in_sizes; (void)n_in; (void)out_size; (void)d_ws; (void)ws_size;
    const float* ts      = (const float*)d_in[0];
    const float* ys      = (const float*)d_in[1];
    const float* eps     = (const float*)d_in[2];
    const float* scale_p = (const float*)d_in[3];
    const float* fw0     = (const float*)d_in[4];
    const float* fb0     = (const float*)d_in[5];
    const float* fw1     = (const float*)d_in[6];
    const float* fb1     = (const float*)d_in[7];
    const float* fw2     = (const float*)d_in[8];
    const float* fb2     = (const float*)d_in[9];
    const float* gwi     = (const float*)d_in[10];
    const float* gwh     = (const float*)d_in[11];
    const float* gbv     = (const float*)d_in[12];
    const float* gbn     = (const float*)d_in[13];
    const float* hlw     = (const float*)d_in[14];
    const float* hlb     = (const float*)d_in[15];
    const float* lw0     = (const float*)d_in[16];
    const float* lb0     = (const float*)d_in[17];
    const float* lw1     = (const float*)d_in[18];
    const float* lb1     = (const float*)d_in[19];
    const float* lw2     = (const float*)d_in[20];
    const float* lb2     = (const float*)d_in[21];
    const float* hdw     = (const float*)d_in[22];
    const float* hdb     = (const float*)d_in[23];
    float* out = (float*)d_out;

    hipLaunchKernelGGL(latentode_fused, dim3(NB), dim3(256), 0, stream,
                       ts, ys, eps, scale_p, fw0, fb0, fw1, fb1, fw2, fb2,
                       gwi, gwh, gbv, gbn, hlw, hlb, lw0, lb0, lw1, lb1,
                       lw2, lb2, hdw, hdb, out);
}

// Round 4
// 1450.356 us; speedup vs baseline: 1.0983x; 1.0983x over previous
//
#include <hip/hip_runtime.h>
#include <math.h>

#define NB 256
#define NT 1024
#define ND 32
#define NH 64
#define NL 32
#define DT0 0.4f
#define XB 36   // staged x row: [y0..y31, ts, pad3]

__device__ __forceinline__ float dot4(float4 a, float4 b) {
    return a.x * b.x + a.y * b.y + a.z * b.z + a.w * b.w;
}
__device__ __forceinline__ float fsigm(float x) {
    return __fdividef(1.0f, 1.0f + __expf(-x));
}
__device__ __forceinline__ float ftanh(float x) {
    float cx = fminf(fmaxf(x, -15.0f), 15.0f);
    float e2 = __expf(2.0f * cx);
    return __fdividef(e2 - 1.0f, e2 + 1.0f);
}
__device__ __forceinline__ float fsoftplus(float x) {
    return fmaxf(x, 0.0f) + __logf(1.0f + __expf(-fabsf(x)));
}

extern "C" __global__ void __launch_bounds__(256, 1)
latentode_fused(const float* __restrict__ ts,      // (B,T)
                const float* __restrict__ ys,      // (B,T,D)
                const float* __restrict__ eps,     // (B,L)
                const float* __restrict__ scale_p, // ()
                const float* __restrict__ fw0, const float* __restrict__ fb0,
                const float* __restrict__ fw1, const float* __restrict__ fb1,
                const float* __restrict__ fw2, const float* __restrict__ fb2,
                const float* __restrict__ gwi, const float* __restrict__ gwh,
                const float* __restrict__ gb,  const float* __restrict__ gbn,
                const float* __restrict__ hlw, const float* __restrict__ hlb,
                const float* __restrict__ lw0, const float* __restrict__ lb0,
                const float* __restrict__ lw1, const float* __restrict__ lb1,
                const float* __restrict__ lw2, const float* __restrict__ lb2,
                const float* __restrict__ hdw, const float* __restrict__ hdb,
                float* __restrict__ out)
{
    const int b   = blockIdx.x;
    const int tid = threadIdx.x;
    const int w   = tid >> 6;
    const int ln  = tid & 63;

    __shared__ __align__(16) float xb[NT * XB];    // 147456 B staged input
    __shared__ __align__(16) float hbuf[2][64];    // GRU h, double-buffered
    __shared__ __align__(16) float a0b[64];
    __shared__ __align__(16) float a1b[64];
    __shared__ __align__(16) float tmpb[64];
    __shared__ __align__(16) float ybuf[64];
    __shared__ __align__(16) float latb[32];
    __shared__ float redr[32];

    // ---------------- stage ts/ys into LDS (one-time, ~150KB) ----------------
    for (int i = tid; i < NT * 8; i += 256) {
        const int row = i >> 3, q = i & 7;
        *(float4*)&xb[row * XB + q * 4] =
            *(const float4*)(ys + (size_t)(b * NT + row) * ND + q * 4);
    }
    for (int i = tid; i < NT; i += 256) xb[i * XB + 32] = ts[b * NT + i];

    // ---------------- GRU weights: unit u = 16w + (ln>>2), k-part p = ln&3 ----
    const int u = (w << 4) + (ln >> 2);
    const int p = ln & 3;
    // Wh rows u, 64+u, 128+u : k-slice [16p..16p+15] (16B-aligned)
    const float4* whr = (const float4*)(gwh + (u)       * 64 + p * 16);
    const float4* whz = (const float4*)(gwh + (64 + u)  * 64 + p * 16);
    const float4* whn = (const float4*)(gwh + (128 + u) * 64 + p * 16);
    const float4 WR0=whr[0], WR1=whr[1], WR2=whr[2], WR3=whr[3];
    const float4 WZ0=whz[0], WZ1=whz[1], WZ2=whz[2], WZ3=whz[3];
    const float4 WN0=whn[0], WN1=whn[1], WN2=whn[2], WN3=whn[3];
    // Wi rows (33 wide, 4B-aligned): y-slice [8p..8p+7], ts weight only in p==0
    const float* gr = gwi + u * 33;
    const float* gz = gwi + (64 + u) * 33;
    const float* gn = gwi + (128 + u) * 33;
    const int o = 8 * p;
    const float4 RIA = make_float4(gr[1+o], gr[2+o], gr[3+o], gr[4+o]);
    const float4 RIB = make_float4(gr[5+o], gr[6+o], gr[7+o], gr[8+o]);
    const float4 ZIA = make_float4(gz[1+o], gz[2+o], gz[3+o], gz[4+o]);
    const float4 ZIB = make_float4(gz[5+o], gz[6+o], gz[7+o], gz[8+o]);
    const float4 NIA = make_float4(gn[1+o], gn[2+o], gn[3+o], gn[4+o]);
    const float4 NIB = make_float4(gn[5+o], gn[6+o], gn[7+o], gn[8+o]);
    const float RT = (p == 0) ? gr[0] : 0.0f;
    const float ZT = (p == 0) ? gz[0] : 0.0f;
    const float NTW= (p == 0) ? gn[0] : 0.0f;
    const float gbr_ = gb[u], gbz_ = gb[64 + u], gbn_ = gb[128 + u];
    const float bnv  = gbn[u];

    if (tid < 64) hbuf[0][tid] = 0.0f;
    __syncthreads();

    // ---------------- GRU scan: 1 barrier, 1 LDS round-trip per step ----------
    float hreg = 0.0f;
    for (int s = 0; s < NT; ++s) {
        const float* xrow = &xb[s * XB];
        const float4 xA = *(const float4*)(xrow + o);
        const float4 xB = *(const float4*)(xrow + o + 4);
        const float tsv = xrow[32];
        const float4* hv = (const float4*)&hbuf[s & 1][p * 16];
        const float4 h0 = hv[0], h1 = hv[1], h2 = hv[2], h3 = hv[3];

        float ar = dot4(WR0,h0) + dot4(WR1,h1) + dot4(WR2,h2) + dot4(WR3,h3)
                 + dot4(RIA,xA) + dot4(RIB,xB) + RT * tsv;
        float az = dot4(WZ0,h0) + dot4(WZ1,h1) + dot4(WZ2,h2) + dot4(WZ3,h3)
                 + dot4(ZIA,xA) + dot4(ZIB,xB) + ZT * tsv;
        float ahn = dot4(WN0,h0) + dot4(WN1,h1) + dot4(WN2,h2) + dot4(WN3,h3);
        float ain = dot4(NIA,xA) + dot4(NIB,xB) + NTW * tsv;

        // quad butterfly (xor1/xor2 -> DPP quad_perm, cheap)
        ar  += __shfl_xor(ar, 1);  ar  += __shfl_xor(ar, 2);
        az  += __shfl_xor(az, 1);  az  += __shfl_xor(az, 2);
        ahn += __shfl_xor(ahn, 1); ahn += __shfl_xor(ahn, 2);
        ain += __shfl_xor(ain, 1); ain += __shfl_xor(ain, 2);

        const float rg = fsigm(ar + gbr_);
        const float zg = fsigm(az + gbz_);
        const float ng = ftanh(ain + gbn_ + rg * (ahn + bnv));
        hreg = ng + zg * (hreg - ng);
        if (p == 0) hbuf[(s + 1) & 1][u] = hreg;
        __syncthreads();
    }
    // final h in hbuf[0] (NT even)

    // ---------------- context -> latent -> y0 (one-time) ----------------------
    if (tid < 64) {
        const float4* wp = (const float4*)(hlw + tid * 64);
        const float4* hv = (const float4*)&hbuf[0][0];
        float a0 = hlb[tid], a1 = 0.0f;
#pragma unroll
        for (int q = 0; q < 16; q += 2) { a0 += dot4(wp[q], hv[q]); a1 += dot4(wp[q+1], hv[q+1]); }
        tmpb[tid] = a0 + a1;
    }
    __syncthreads();
    float klpart = 0.0f;
    if (tid < 32) {
        const float mean   = tmpb[tid];
        const float logstd = tmpb[32 + tid];
        const float stdv   = __expf(logstd);
        latb[tid] = mean + eps[b * NL + tid] * stdv;
        klpart = 0.5f * (mean * mean + stdv * stdv - 2.0f * logstd - 1.0f);
    }
    __syncthreads();
    if (tid < 64) {
        const float4* wp = (const float4*)(lw0 + tid * 32);
        const float4* lv = (const float4*)latb;
        float a0 = lb0[tid], a1 = 0.0f;
#pragma unroll
        for (int q = 0; q < 8; q += 2) { a0 += dot4(wp[q], lv[q]); a1 += dot4(wp[q+1], lv[q+1]); }
        a0b[tid] = fmaxf(a0 + a1, 0.0f);
    }
    __syncthreads();
    if (tid < 64) {
        const float4* wp = (const float4*)(lw1 + tid * 64);
        const float4* av = (const float4*)a0b;
        float a0 = lb1[tid], a1 = 0.0f;
#pragma unroll
        for (int q = 0; q < 16; q += 2) { a0 += dot4(wp[q], av[q]); a1 += dot4(wp[q+1], av[q+1]); }
        a1b[tid] = fmaxf(a0 + a1, 0.0f);
    }
    __syncthreads();
    if (tid < 64) {
        const float4* wp = (const float4*)(lw2 + tid * 64);
        const float4* tv = (const float4*)a1b;
        float a0 = lb2[tid], a1 = 0.0f;
#pragma unroll
        for (int q = 0; q < 16; q += 2) { a0 += dot4(wp[q], tv[q]); a1 += dot4(wp[q+1], tv[q+1]); }
        ybuf[tid] = a0 + a1;   // y0
    }
    __syncthreads();

    // ---------------- Euler weights: er/ep 4-way split, hd 8-way --------------
    const int er = tid >> 2, ep = tid & 3;
    const float4* q0 = (const float4*)(fw0 + er * 64 + ep * 16);
    const float4 E00=q0[0], E01=q0[1], E02=q0[2], E03=q0[3];
    const float4* q1 = (const float4*)(fw1 + er * 64 + ep * 16);
    const float4 E10=q1[0], E11=q1[1], E12=q1[2], E13=q1[3];
    const float4* q2 = (const float4*)(fw2 + er * 64 + ep * 16);
    const float4 E20=q2[0], E21=q2[1], E22=q2[2], E23=q2[3];
    const float b0 = fb0[er], b1 = fb1[er], b2 = fb2[er];
    const int hr2 = tid >> 3, hp = tid & 7;
    const float4* qh = (const float4*)(hdw + hr2 * 64 + hp * 8);
    const float4 HD0 = qh[0], HD1 = qh[1];
    const float hdbias = hdb[hr2];
    const float dts = DT0 * scale_p[0];
    float ylocal = (ep == 0) ? ybuf[er] : 0.0f;   // y[er] owned by lane (er,0)
    float rec = 0.0f;

    // ---------------- Euler scan: 3 thin phases, 3 barriers -------------------
    for (int s = 0; s < NT; ++s) {
        // P1: layer0 (all lanes) + hd projection of y_s (recon vs ys[s-1])
        {
            const float4* yv = (const float4*)ybuf;
            float l0 = dot4(E00, yv[ep*4+0]) + dot4(E01, yv[ep*4+1])
                     + dot4(E02, yv[ep*4+2]) + dot4(E03, yv[ep*4+3]);
            l0 += __shfl_xor(l0, 1);
            l0 += __shfl_xor(l0, 2);
            float ph = dot4(HD0, yv[hp*2+0]) + dot4(HD1, yv[hp*2+1]);
            ph += __shfl_xor(ph, 1);
            ph += __shfl_xor(ph, 2);
            ph += __shfl_xor(ph, 4);
            if (ep == 0) a0b[er] = fsoftplus(l0 + b0);
            if (hp == 0 && s > 0) {
                const float d = xb[(s - 1) * XB + hr2] - (ph + hdbias);
                rec += d * d;
            }
        }
        __syncthreads();
        // P2: layer1
        {
            const float4* av = (const float4*)a0b;
            float l1 = dot4(E10, av[ep*4+0]) + dot4(E11, av[ep*4+1])
                     + dot4(E12, av[ep*4+2]) + dot4(E13, av[ep*4+3]);
            l1 += __shfl_xor(l1, 1);
            l1 += __shfl_xor(l1, 2);
            if (ep == 0) a1b[er] = fsoftplus(l1 + b1);
        }
        __syncthreads();
        // P3: layer2 + y update (lane (er,0) keeps y in register)
        {
            const float4* bv = (const float4*)a1b;
            float l2 = dot4(E20, bv[ep*4+0]) + dot4(E21, bv[ep*4+1])
                     + dot4(E22, bv[ep*4+2]) + dot4(E23, bv[ep*4+3]);
            l2 += __shfl_xor(l2, 1);
            l2 += __shfl_xor(l2, 2);
            if (ep == 0) {
                ylocal += dts * ftanh(l2 + b2);
                ybuf[er] = ylocal;
            }
        }
        __syncthreads();
    }

    // epilogue: hd of y_T vs ys[T-1]
    {
        const float4* yv = (const float4*)ybuf;
        float ph = dot4(HD0, yv[hp*2+0]) + dot4(HD1, yv[hp*2+1]);
        ph += __shfl_xor(ph, 1);
        ph += __shfl_xor(ph, 2);
        ph += __shfl_xor(ph, 4);
        if (hp == 0) {
            const float d = xb[(NT - 1) * XB + hr2] - (ph + hdbias);
            rec += d * d;
            redr[hr2] = rec;
        }
    }
    // KL reduce (lanes 0..31 of wave 0)
    float klv = klpart;
    klv += __shfl_xor(klv, 1);
    klv += __shfl_xor(klv, 2);
    klv += __shfl_xor(klv, 4);
    klv += __shfl_xor(klv, 8);
    klv += __shfl_xor(klv, 16);
    __syncthreads();
    if (tid == 0) {
        float rs = 0.0f;
#pragma unroll
        for (int k2 = 0; k2 < 32; ++k2) rs += redr[k2];
        out[b] = 0.5f * rs + klv;
    }
}

extern "C" void kernel_launch(void* const* d_in, const int* in_sizes, int n_in,
                              void* d_out, int out_size, void* d_ws, size_t ws_size,
                              hipStream_t stream) {
    (void)in_sizes; (void)n_in; (void)out_size; (void)d_ws; (void)ws_size;
    const float* ts      = (const float*)d_in[0];
    const float* ys      = (const float*)d_in[1];
    const float* eps     = (const float*)d_in[2];
    const float* scale_p = (const float*)d_in[3];
    const float* fw0     = (const float*)d_in[4];
    const float* fb0     = (const float*)d_in[5];
    const float* fw1     = (const float*)d_in[6];
    const float* fb1     = (const float*)d_in[7];
    const float* fw2     = (const float*)d_in[8];
    const float* fb2     = (const float*)d_in[9];
    const float* gwi     = (const float*)d_in[10];
    const float* gwh     = (const float*)d_in[11];
    const float* gbv     = (const float*)d_in[12];
    const float* gbn     = (const float*)d_in[13];
    const float* hlw     = (const float*)d_in[14];
    const float* hlb     = (const float*)d_in[15];
    const float* lw0     = (const float*)d_in[16];
    const float* lb0     = (const float*)d_in[17];
    const float* lw1     = (const float*)d_in[18];
    const float* lb1     = (const float*)d_in[19];
    const float* lw2     = (const float*)d_in[20];
    const float* lb2     = (const float*)d_in[21];
    const float* hdw     = (const float*)d_in[22];
    const float* hdb     = (const float*)d_in[23];
    float* out = (float*)d_out;

    hipLaunchKernelGGL(latentode_fused, dim3(NB), dim3(256), 0, stream,
                       ts, ys, eps, scale_p, fw0, fb0, fw1, fb1, fw2, fb2,
                       gwi, gwh, gbv, gbn, hlw, hlb, lw0, lb0, lw1, lb1,
                       lw2, lb2, hdw, hdb, out);
}

// Round 6
// 1165.397 us; speedup vs baseline: 1.3668x; 1.2445x over previous
//
#include <hip/hip_runtime.h>
#include <math.h>

#define NB 256
#define NT 1024
#define ND 32
#define NH 64
#define NL 32
#define DT0 0.4f
#define XB 36   // staged x row: [y0..y31, ts, pad3]

__device__ __forceinline__ float dot4(float4 a, float4 b) {
    return a.x * b.x + a.y * b.y + a.z * b.z + a.w * b.w;
}
__device__ __forceinline__ float fsigm(float x) {
    return __fdividef(1.0f, 1.0f + __expf(-x));
}
__device__ __forceinline__ float ftanh(float x) {
    float cx = fminf(fmaxf(x, -15.0f), 15.0f);
    float e2 = __expf(2.0f * cx);
    return __fdividef(e2 - 1.0f, e2 + 1.0f);
}
__device__ __forceinline__ float fsoftplus(float x) {
    return fmaxf(x, 0.0f) + __logf(1.0f + __expf(-fabsf(x)));
}

// DPP cross-lane adds on the VALU pipe (no LDS/bpermute latency).
// 0xB1 = quad_perm(1,0,3,2) -> xor1 ; 0x4E = quad_perm(2,3,0,1) -> xor2
// 0x104 = row_shl:4 -> lane i receives lane i+4 (0 beyond row w/ bound_ctrl);
//         combined with quad sums this completes an 8-lane group total at
//         lanes hp==0 (lane 0 gets quad1's sum, lane 8 gets quad3's). The
//         round-4 bug: row_ror:4 (0x124) moves lane i-4 -> i, i.e. lane 0
//         received quad3's sum from the NEIGHBORING group.
template <int CTRL>
__device__ __forceinline__ float dpp_add(float x) {
    int t = __builtin_amdgcn_update_dpp(0, __float_as_int(x), CTRL, 0xF, 0xF, true);
    return x + __int_as_float(t);
}
__device__ __forceinline__ float quad_reduce(float x) {
    x = dpp_add<0xB1>(x);
    x = dpp_add<0x4E>(x);
    return x;
}

extern "C" __global__ void __launch_bounds__(256, 1)
latentode_fused(const float* __restrict__ ts,      // (B,T)
                const float* __restrict__ ys,      // (B,T,D)
                const float* __restrict__ eps,     // (B,L)
                const float* __restrict__ scale_p, // ()
                const float* __restrict__ fw0, const float* __restrict__ fb0,
                const float* __restrict__ fw1, const float* __restrict__ fb1,
                const float* __restrict__ fw2, const float* __restrict__ fb2,
                const float* __restrict__ gwi, const float* __restrict__ gwh,
                const float* __restrict__ gb,  const float* __restrict__ gbn,
                const float* __restrict__ hlw, const float* __restrict__ hlb,
                const float* __restrict__ lw0, const float* __restrict__ lb0,
                const float* __restrict__ lw1, const float* __restrict__ lb1,
                const float* __restrict__ lw2, const float* __restrict__ lb2,
                const float* __restrict__ hdw, const float* __restrict__ hdb,
                float* __restrict__ out)
{
    const int b   = blockIdx.x;
    const int tid = threadIdx.x;
    const int w   = tid >> 6;
    const int ln  = tid & 63;

    __shared__ __align__(16) float xb[NT * XB];    // 147456 B staged input
    __shared__ __align__(16) float hbuf[2][64];    // GRU h, double-buffered
    __shared__ __align__(16) float a0b[64];
    __shared__ __align__(16) float a1b[64];
    __shared__ __align__(16) float tmpb[64];
    __shared__ __align__(16) float ybuf[64];
    __shared__ __align__(16) float latb[32];
    __shared__ float redr[32];

    // ---------------- stage ts/ys into LDS (one-time) -------------------------
    for (int i = tid; i < NT * 8; i += 256) {
        const int row = i >> 3, q = i & 7;
        *(float4*)&xb[row * XB + q * 4] =
            *(const float4*)(ys + (size_t)(b * NT + row) * ND + q * 4);
    }
    for (int i = tid; i < NT; i += 256) xb[i * XB + 32] = ts[b * NT + i];

    // ---------------- GRU weights: unit u = 16w + (ln>>2), k-part p = ln&3 ----
    const int u = (w << 4) + (ln >> 2);
    const int p = ln & 3;
    const float4* whr = (const float4*)(gwh + (u)       * 64 + p * 16);
    const float4* whz = (const float4*)(gwh + (64 + u)  * 64 + p * 16);
    const float4* whn = (const float4*)(gwh + (128 + u) * 64 + p * 16);
    const float4 WR0=whr[0], WR1=whr[1], WR2=whr[2], WR3=whr[3];
    const float4 WZ0=whz[0], WZ1=whz[1], WZ2=whz[2], WZ3=whz[3];
    const float4 WN0=whn[0], WN1=whn[1], WN2=whn[2], WN3=whn[3];
    const float* gr = gwi + u * 33;
    const float* gz = gwi + (64 + u) * 33;
    const float* gn = gwi + (128 + u) * 33;
    const int o = 8 * p;
    const float4 RIA = make_float4(gr[1+o], gr[2+o], gr[3+o], gr[4+o]);
    const float4 RIB = make_float4(gr[5+o], gr[6+o], gr[7+o], gr[8+o]);
    const float4 ZIA = make_float4(gz[1+o], gz[2+o], gz[3+o], gz[4+o]);
    const float4 ZIB = make_float4(gz[5+o], gz[6+o], gz[7+o], gz[8+o]);
    const float4 NIA = make_float4(gn[1+o], gn[2+o], gn[3+o], gn[4+o]);
    const float4 NIB = make_float4(gn[5+o], gn[6+o], gn[7+o], gn[8+o]);
    const float RT  = (p == 0) ? gr[0] : 0.0f;
    const float ZT  = (p == 0) ? gz[0] : 0.0f;
    const float NTW = (p == 0) ? gn[0] : 0.0f;
    const float gbr_ = gb[u], gbz_ = gb[64 + u], gbn_ = gb[128 + u];
    const float bnv  = gbn[u];

    if (tid < 64) hbuf[0][tid] = 0.0f;
    __syncthreads();

    // ---------------- GRU scan: 1 barrier/step, DPP reductions -----------------
    float hreg = 0.0f;
    float4 xA = *(const float4*)(&xb[0] + o);
    float4 xB = *(const float4*)(&xb[0] + o + 4);
    float tsv = xb[32];
    for (int s = 0; s < NT; ++s) {
        // prefetch next step's x into regs (independent of h-chain)
        const int sn = (s + 1 < NT) ? (s + 1) : s;
        const float* xrown = &xb[sn * XB];
        const float4 nxA = *(const float4*)(xrown + o);
        const float4 nxB = *(const float4*)(xrown + o + 4);
        const float ntsv = xrown[32];

        const float4* hv = (const float4*)&hbuf[s & 1][p * 16];
        const float4 h0 = hv[0], h1 = hv[1], h2 = hv[2], h3 = hv[3];

        float ar = dot4(WR0,h0) + dot4(WR1,h1) + dot4(WR2,h2) + dot4(WR3,h3)
                 + dot4(RIA,xA) + dot4(RIB,xB) + RT * tsv;
        float az = dot4(WZ0,h0) + dot4(WZ1,h1) + dot4(WZ2,h2) + dot4(WZ3,h3)
                 + dot4(ZIA,xA) + dot4(ZIB,xB) + ZT * tsv;
        float ahn = dot4(WN0,h0) + dot4(WN1,h1) + dot4(WN2,h2) + dot4(WN3,h3);
        float ain = dot4(NIA,xA) + dot4(NIB,xB) + NTW * tsv;

        ar  = quad_reduce(ar);
        az  = quad_reduce(az);
        ahn = quad_reduce(ahn);
        ain = quad_reduce(ain);

        const float rg = fsigm(ar + gbr_);
        const float zg = fsigm(az + gbz_);
        const float ng = ftanh(ain + gbn_ + rg * (ahn + bnv));
        hreg = ng + zg * (hreg - ng);
        if (p == 0) hbuf[(s + 1) & 1][u] = hreg;
        xA = nxA; xB = nxB; tsv = ntsv;
        __syncthreads();
    }
    // final h in hbuf[0] (NT even)

    // ---------------- context -> latent -> y0 (one-time) ----------------------
    if (tid < 64) {
        const float4* wp = (const float4*)(hlw + tid * 64);
        const float4* hv = (const float4*)&hbuf[0][0];
        float a0 = hlb[tid], a1 = 0.0f;
#pragma unroll
        for (int q = 0; q < 16; q += 2) { a0 += dot4(wp[q], hv[q]); a1 += dot4(wp[q+1], hv[q+1]); }
        tmpb[tid] = a0 + a1;
    }
    __syncthreads();
    float klpart = 0.0f;
    if (tid < 32) {
        const float mean   = tmpb[tid];
        const float logstd = tmpb[32 + tid];
        const float stdv   = __expf(logstd);
        latb[tid] = mean + eps[b * NL + tid] * stdv;
        klpart = 0.5f * (mean * mean + stdv * stdv - 2.0f * logstd - 1.0f);
    }
    __syncthreads();
    if (tid < 64) {
        const float4* wp = (const float4*)(lw0 + tid * 32);
        const float4* lv = (const float4*)latb;
        float a0 = lb0[tid], a1 = 0.0f;
#pragma unroll
        for (int q = 0; q < 8; q += 2) { a0 += dot4(wp[q], lv[q]); a1 += dot4(wp[q+1], lv[q+1]); }
        a0b[tid] = fmaxf(a0 + a1, 0.0f);
    }
    __syncthreads();
    if (tid < 64) {
        const float4* wp = (const float4*)(lw1 + tid * 64);
        const float4* av = (const float4*)a0b;
        float a0 = lb1[tid], a1 = 0.0f;
#pragma unroll
        for (int q = 0; q < 16; q += 2) { a0 += dot4(wp[q], av[q]); a1 += dot4(wp[q+1], av[q+1]); }
        a1b[tid] = fmaxf(a0 + a1, 0.0f);
    }
    __syncthreads();
    if (tid < 64) {
        const float4* wp = (const float4*)(lw2 + tid * 64);
        const float4* tv = (const float4*)a1b;
        float a0 = lb2[tid], a1 = 0.0f;
#pragma unroll
        for (int q = 0; q < 16; q += 2) { a0 += dot4(wp[q], tv[q]); a1 += dot4(wp[q+1], tv[q+1]); }
        ybuf[tid] = a0 + a1;   // y0
    }
    __syncthreads();

    // ---------------- Euler weights: er/ep 4-way split, hd 8-way --------------
    const int er = tid >> 2, ep = tid & 3;
    const float4* q0 = (const float4*)(fw0 + er * 64 + ep * 16);
    const float4 E00=q0[0], E01=q0[1], E02=q0[2], E03=q0[3];
    const float4* q1 = (const float4*)(fw1 + er * 64 + ep * 16);
    const float4 E10=q1[0], E11=q1[1], E12=q1[2], E13=q1[3];
    const float4* q2 = (const float4*)(fw2 + er * 64 + ep * 16);
    const float4 E20=q2[0], E21=q2[1], E22=q2[2], E23=q2[3];
    const float b0 = fb0[er], b1 = fb1[er], b2 = fb2[er];
    const int hr2 = tid >> 3, hp = tid & 7;
    const float4* qh = (const float4*)(hdw + hr2 * 64 + hp * 8);
    const float4 HD0 = qh[0], HD1 = qh[1];
    const float hdbias = hdb[hr2];
    const float dts = DT0 * scale_p[0];
    float ylocal = (ep == 0) ? ybuf[er] : 0.0f;   // y[er] owned by lane (er,0)
    float rec = 0.0f;

    // ---------------- Euler scan: 3 phases, DPP reductions --------------------
    for (int s = 0; s < NT; ++s) {
        // P1: layer0 from y_s
        {
            const float4* yv = (const float4*)ybuf;
            float l0 = dot4(E00, yv[ep*4+0]) + dot4(E01, yv[ep*4+1])
                     + dot4(E02, yv[ep*4+2]) + dot4(E03, yv[ep*4+3]);
            l0 = quad_reduce(l0);
            if (ep == 0) a0b[er] = fsoftplus(l0 + b0);
        }
        __syncthreads();
        // P2: layer1 from a0  |  hd projection of y_s + recon vs ys[s-1]
        {
            const float4* av = (const float4*)a0b;
            float l1 = dot4(E10, av[ep*4+0]) + dot4(E11, av[ep*4+1])
                     + dot4(E12, av[ep*4+2]) + dot4(E13, av[ep*4+3]);
            l1 = quad_reduce(l1);

            const float4* yv = (const float4*)ybuf;   // y_s still valid (P3 not run)
            float ph = dot4(HD0, yv[hp*2+0]) + dot4(HD1, yv[hp*2+1]);
            ph = quad_reduce(ph);
            ph = dpp_add<0x104>(ph);   // row_shl:4 — group total valid at hp==0
            if (ep == 0) a1b[er] = fsoftplus(l1 + b1);
            if (hp == 0 && s > 0) {
                const float d = xb[(s - 1) * XB + hr2] - (ph + hdbias);
                rec += d * d;
            }
        }
        __syncthreads();
        // P3: layer2 + y update (lane (er,0) keeps y in register)
        {
            const float4* bv = (const float4*)a1b;
            float l2 = dot4(E20, bv[ep*4+0]) + dot4(E21, bv[ep*4+1])
                     + dot4(E22, bv[ep*4+2]) + dot4(E23, bv[ep*4+3]);
            l2 = quad_reduce(l2);
            if (ep == 0) {
                ylocal += dts * ftanh(l2 + b2);
                ybuf[er] = ylocal;
            }
        }
        __syncthreads();
    }

    // epilogue: hd of y_T vs ys[T-1]
    {
        const float4* yv = (const float4*)ybuf;
        float ph = dot4(HD0, yv[hp*2+0]) + dot4(HD1, yv[hp*2+1]);
        ph = quad_reduce(ph);
        ph = dpp_add<0x104>(ph);   // row_shl:4
        if (hp == 0) {
            const float d = xb[(NT - 1) * XB + hr2] - (ph + hdbias);
            rec += d * d;
            redr[hr2] = rec;
        }
    }
    // KL reduce (lanes 0..31 of wave 0)
    float klv = klpart;
    klv += __shfl_xor(klv, 1);
    klv += __shfl_xor(klv, 2);
    klv += __shfl_xor(klv, 4);
    klv += __shfl_xor(klv, 8);
    klv += __shfl_xor(klv, 16);
    __syncthreads();
    if (tid == 0) {
        float rs = 0.0f;
#pragma unroll
        for (int k2 = 0; k2 < 32; ++k2) rs += redr[k2];
        out[b] = 0.5f * rs + klv;
    }
}

extern "C" void kernel_launch(void* const* d_in, const int* in_sizes, int n_in,
                              void* d_out, int out_size, void* d_ws, size_t ws_size,
                              hipStream_t stream) {
    (void)in_sizes; (void)n_in; (void)out_size; (void)d_ws; (void)ws_size;
    const float* ts      = (const float*)d_in[0];
    const float* ys      = (const float*)d_in[1];
    const float* eps     = (const float*)d_in[2];
    const float* scale_p = (const float*)d_in[3];
    const float* fw0     = (const float*)d_in[4];
    const float* fb0     = (const float*)d_in[5];
    const float* fw1     = (const float*)d_in[6];
    const float* fb1     = (const float*)d_in[7];
    const float* fw2     = (const float*)d_in[8];
    const float* fb2     = (const float*)d_in[9];
    const float* gwi     = (const float*)d_in[10];
    const float* gwh     = (const float*)d_in[11];
    const float* gbv     = (const float*)d_in[12];
    const float* gbn     = (const float*)d_in[13];
    const float* hlw     = (const float*)d_in[14];
    const float* hlb     = (const float*)d_in[15];
    const float* lw0     = (const float*)d_in[16];
    const float* lb0     = (const float*)d_in[17];
    const float* lw1     = (const float*)d_in[18];
    const float* lb1     = (const float*)d_in[19];
    const float* lw2     = (const float*)d_in[20];
    const float* lb2     = (const float*)d_in[21];
    const float* hdw     = (const float*)d_in[22];
    const float* hdb     = (const float*)d_in[23];
    float* out = (float*)d_out;

    hipLaunchKernelGGL(latentode_fused, dim3(NB), dim3(256), 0, stream,
                       ts, ys, eps, scale_p, fw0, fb0, fw1, fb1, fw2, fb2,
                       gwi, gwh, gbv, gbn, hlw, hlb, lw0, lb0, lw1, lb1,
                       lw2, lb2, hdw, hdb, out);
}